// Round 5
// baseline (375.415 us; speedup 1.0000x reference)
//
#include <hip/hip_runtime.h>
#include <stdint.h>

// Problem constants
#define S_LEN   1024
#define D_MODEL 4096
#define NHQ     32
#define NKV     8
#define HD      128
#define NTOK    2048   // B*S
#define NQKV    6144   // 4096 q + 1024 k + 1024 v
#define SM_SCALE 0.08838834764831843f

typedef __attribute__((ext_vector_type(8))) __bf16 bf16x8;
typedef __attribute__((ext_vector_type(4))) float f32x4;

__device__ __forceinline__ unsigned short f2bf(float f) {
  union { float f; unsigned u; } x; x.f = f;
  unsigned r = x.u + 0x7fffu + ((x.u >> 16) & 1u);
  return (unsigned short)(r >> 16);
}

__device__ __forceinline__ void gload_lds16(const void* g, void* l) {
  __builtin_amdgcn_global_load_lds((__attribute__((address_space(1))) void*)g,
                                   (__attribute__((address_space(3))) void*)l,
                                   16, 0, 0);
}

// ---------------- f32 -> bf16 straight conversion (vectorized) ----------------
__global__ void k_f32_to_bf16(const float* __restrict__ in,
                              unsigned short* __restrict__ out, int n8) {
  int i = blockIdx.x * blockDim.x + threadIdx.x;
  if (i >= n8) return;
  const float4* p = (const float4*)(in + (size_t)i * 8);
  float4 v0 = p[0], v1 = p[1];
  uint4 o;
  o.x = f2bf(v0.x) | ((unsigned)f2bf(v0.y) << 16);
  o.y = f2bf(v0.z) | ((unsigned)f2bf(v0.w) << 16);
  o.z = f2bf(v1.x) | ((unsigned)f2bf(v1.y) << 16);
  o.w = f2bf(v1.z) | ((unsigned)f2bf(v1.w) << 16);
  *(uint4*)(out + (size_t)i * 8) = o;
}

// ---------------- f32 [R][C] -> bf16 [C][R] tiled transpose ----------------
__global__ void k_transpose(const float* __restrict__ in,
                            unsigned short* __restrict__ out, int R, int C) {
  __shared__ float t[32][33];
  int c = threadIdx.x & 31, r0 = threadIdx.x >> 5;   // 256 threads: 8 rows x 32 cols
  int cb = blockIdx.x * 32, rb = blockIdx.y * 32;
#pragma unroll
  for (int i = 0; i < 4; ++i) {
    int r = r0 + i * 8;
    t[r][c] = in[(size_t)(rb + r) * C + cb + c];
  }
  __syncthreads();
#pragma unroll
  for (int i = 0; i < 4; ++i) {
    int r = r0 + i * 8;
    out[(size_t)(cb + r) * R + rb + c] = f2bf(t[c][r]);
  }
}

// ================= 256x256 m201-template bf16 GEMM ============================
// C[M][ldc](f32) = A[M][K](bf16) * Bt[N][K](bf16)^T, optional K-split w/ atomics
// 512 threads = 8 waves (2M x 4N), per-wave 128x64 out, BK=64, dbuf over K-tiles.
// Per K-tile: 4 phases = quadrants (mh, kh-half). Phase = { ds_read this
// phase's frags (8 or 4); issue 1 half-tile stage; [vmcnt(4) gate at q1/q3];
// s_barrier; lgkmcnt(0)+sched_barrier; setprio(1); 16 MFMA; setprio(0);
// s_barrier }.  B-frags reused across mh-phases. Counted vmcnt never 0.
// Race audit: every staged region's readers pass lgkm(0) before a barrier that
// precedes the staging issue; every read passes a barrier preceded by a
// per-wave vmcnt gate covering the loads that filled it.
// LDS 128 KiB, 64-B rows, slot-swizzle slot^=(row>>1)&3 (0 conflicts, r2-verified).

#define STG(Gptr, rowbase, ksrc, half, bufi, matoff)                            \
  { int kcl = (ksrc) < NT ? (ksrc) : NT - 1;                                    \
    _Pragma("unroll")                                                           \
    for (int i_ = 0; i_ < 2; ++i_) {                                            \
      int lin = i_ * 512 + tid;                                                 \
      int r_ = lin >> 2, slot = lin & 3;                                        \
      int sw = slot ^ ((r_ >> 1) & 3);                                          \
      gload_lds16(Gptr + (size_t)((rowbase) + r_) * Kstride + k0e + kcl * 64 + (half) * 32 + sw * 8, \
                  smem + (bufi) * 65536 + (matoff) + (half) * 16384 + lin * 16); \
    } }

#define RD_A(mh, kh, bufi)                                                      \
  _Pragma("unroll")                                                             \
  for (int mf = 0; mf < 4; ++mf) {                                              \
    int row = wr * 128 + (mh) * 64 + mf * 16 + lr;                              \
    af[mf] = *(const bf16x8*)(smem + (bufi) * 65536 + (kh) * 16384 + row * 64   \
                              + ((lg * 16) ^ (((row >> 1) & 3) << 4)));         \
  }

#define RD_B(kh, bufi)                                                          \
  _Pragma("unroll")                                                             \
  for (int nf = 0; nf < 4; ++nf) {                                              \
    int row = wc * 64 + nf * 16 + lr;                                           \
    bf[nf] = *(const bf16x8*)(smem + (bufi) * 65536 + 32768 + (kh) * 16384 + row * 64 \
                              + ((lg * 16) ^ (((row >> 1) & 3) << 4)));         \
  }

#define PHASE_TAIL(mh, GATE)                                                    \
  if (GATE) asm volatile("s_waitcnt vmcnt(4)" ::: "memory");                    \
  __builtin_amdgcn_s_barrier();                                                 \
  asm volatile("s_waitcnt lgkmcnt(0)" ::: "memory");                            \
  __builtin_amdgcn_sched_barrier(0);                                            \
  __builtin_amdgcn_s_setprio(1);                                                \
  _Pragma("unroll")                                                             \
  for (int mf = 0; mf < 4; ++mf)                                                \
    _Pragma("unroll")                                                           \
    for (int nf = 0; nf < 4; ++nf)                                              \
      acc[(mh) * 4 + mf][nf] = __builtin_amdgcn_mfma_f32_16x16x32_bf16(         \
          af[mf], bf[nf], acc[(mh) * 4 + mf][nf], 0, 0, 0);                     \
  __builtin_amdgcn_s_setprio(0);                                                \
  __builtin_amdgcn_s_barrier();

__global__ __launch_bounds__(512, 2) void k_gemm256(
    const unsigned short* __restrict__ A,
    const unsigned short* __restrict__ Bt,
    float* __restrict__ C, int Kstride, int ldc, int nbx, int ksplit, int NT,
    int use_atomic) {
  extern __shared__ __align__(16) char smem[];
  int tid = threadIdx.x;
  int l = tid & 63;
  int w = tid >> 6;
  int lr = l & 15, lg = l >> 4;
  int wr = w >> 2, wc = w & 3;
  // XCD-aware bijective swizzle (gridDim.x % 8 == 0 for all launches)
  int nwg = gridDim.x;
  int q8 = nwg >> 3;
  int o = blockIdx.x;
  int wg = (o & 7) * q8 + (o >> 3);
  int tiles = nwg / ksplit;
  int ks = wg / tiles;
  int wgt = wg - ks * tiles;
  int by = wgt / nbx, bx = wgt - by * nbx;
  int bm = by * 256, bn = bx * 256;
  int k0e = ks * NT * 64;

  f32x4 acc[8][4] = {};
  bf16x8 af[4], bf[4];

  // prologue: stage all 4 half-tiles of kt=0 into buf0 (8 loads);
  // vmcnt(4) forces A-h0 + B-h0 complete; barrier publishes.
  STG(A, bm, 0, 0, 0, 0); STG(Bt, bn, 0, 0, 0, 32768);
  STG(A, bm, 0, 1, 0, 0); STG(Bt, bn, 0, 1, 0, 32768);
  asm volatile("s_waitcnt vmcnt(4)" ::: "memory");
  __builtin_amdgcn_s_barrier();

  for (int kt = 0; kt < NT; ++kt) {
    int cur = kt & 1;
    // q0: (mh0, kh0) — 8 reads
    RD_A(0, 0, cur) RD_B(0, cur)
    STG(A, bm, kt + 1, 0, cur ^ 1, 0)
    PHASE_TAIL(0, 0)
    // q1: (mh1, kh0) — 4 reads, reuse bf; gate covers prev-tile h1
    RD_A(1, 0, cur)
    STG(Bt, bn, kt + 1, 0, cur ^ 1, 32768)
    PHASE_TAIL(1, 1)
    // q2: (mh0, kh1) — 8 reads
    RD_A(0, 1, cur) RD_B(1, cur)
    STG(A, bm, kt + 1, 1, cur ^ 1, 0)
    PHASE_TAIL(0, 0)
    // q3: (mh1, kh1) — 4 reads; gate covers next-tile h0
    RD_A(1, 1, cur)
    STG(Bt, bn, kt + 1, 1, cur ^ 1, 32768)
    PHASE_TAIL(1, 1)
  }

  // epilogue: C/D layout col=lane&15, row=(lane>>4)*4+j [m89-verified]
#pragma unroll
  for (int mh = 0; mh < 2; ++mh)
#pragma unroll
    for (int mf = 0; mf < 4; ++mf)
#pragma unroll
      for (int nf = 0; nf < 4; ++nf)
#pragma unroll
        for (int j = 0; j < 4; ++j) {
          size_t idx = (size_t)(bm + wr * 128 + mh * 64 + mf * 16 + lg * 4 + j) * ldc +
                       bn + wc * 64 + nf * 16 + lr;
          float v = acc[mh * 4 + mf][nf][j];
          if (use_atomic) atomicAdd(&C[idx], v);
          else C[idx] = v;
        }
}

// ---------------- RMSNorm + RoPE, f32 qkv -> bf16 head-major ----------------
// out layout: [B][nheads][S][HD]; oscale folds softmax scale into Q
__global__ void k_norm_rope(const float* __restrict__ qkv, const float* __restrict__ w,
                            const int* __restrict__ positions,
                            unsigned short* __restrict__ out, int nheads, int colbase,
                            float oscale) {
  int wid = blockIdx.x * 4 + (threadIdx.x >> 6);
  int lane = threadIdx.x & 63;
  int token = wid / nheads, head = wid - token * nheads;
  const float* src = qkv + (size_t)token * NQKV + colbase + head * HD;
  float e0 = src[lane], e1 = src[lane + 64];
  float ss = e0 * e0 + e1 * e1;
#pragma unroll
  for (int m = 1; m < 64; m <<= 1) ss += __shfl_xor(ss, m, 64);
  float rs = rsqrtf(ss * (1.0f / 128.0f) + 1e-6f);
  float n0 = e0 * rs * w[lane], n1 = e1 * rs * w[lane + 64];
  int pos = positions[token];
  // inv_freq = theta^(-lane/64) ; log2(1e6) = 19.931568569324174
  float invf = exp2f((float)lane * (-19.931568569324174f / 64.0f));
  float ang = (float)pos * invf;
  float sv, cv;
  sincosf(ang, &sv, &cv);
  float o0 = (n0 * cv - n1 * sv) * oscale;
  float o1 = (n1 * cv + n0 * sv) * oscale;
  int b = token >> 10, s = token & 1023;
  size_t ob = ((size_t)(b * nheads + head) * S_LEN + s) * HD;
  out[ob + lane] = f2bf(o0);
  out[ob + 64 + lane] = f2bf(o1);
}

// ---------------- V transpose: f32 qkv v-cols -> bf16 [b][kv][d][s] ----------
__global__ void k_v_transpose(const float* __restrict__ qkv, unsigned short* __restrict__ vt) {
  __shared__ float t[32][33];
  int slice = blockIdx.z;              // b*8 + kh
  int b = slice >> 3, kh = slice & 7;
  const float* in = qkv + (size_t)(b * S_LEN) * NQKV + 5120 + kh * HD;
  unsigned short* out = vt + (size_t)slice * HD * S_LEN;
  int c = threadIdx.x & 31, r0 = threadIdx.x >> 5;
  int s0 = blockIdx.y * 32, d0 = blockIdx.x * 32;
#pragma unroll
  for (int i = 0; i < 4; ++i) {
    int r = r0 + i * 8;
    t[r][c] = in[(size_t)(s0 + r) * NQKV + d0 + c];
  }
  __syncthreads();
#pragma unroll
  for (int i = 0; i < 4; ++i) {
    int r = r0 + i * 8;
    out[(size_t)(d0 + r) * S_LEN + s0 + c] = f2bf(t[c][r]);
  }
}

// ---------------- causal GQA flash attention ----------------
// Q: [B][32][S][128] bf16 (pre-scaled by SM_SCALE) ; K: [B][8][S][128] bf16 ;
// VT: [B][8][128][S] bf16 ; out: attn [NTOK][4096] bf16
// KVBLK=64, XOR-swizzled LDS (byte ^= (row&7)<<4, both-sides), strip pairing
// (bx, 15-bx) for uniform per-block work.
__global__ __launch_bounds__(256) void k_attn(const unsigned short* __restrict__ qh,
                                              const unsigned short* __restrict__ kbuf,
                                              const unsigned short* __restrict__ vtbuf,
                                              unsigned short* __restrict__ attn_out) {
  __shared__ __align__(16) unsigned short k_lds[64 * 128];   // [kv=64][d=128]
  __shared__ __align__(16) unsigned short v_lds[128 * 64];   // [d=128][kv=64]
  __shared__ __align__(16) unsigned short p_lds[4][16 * 64]; // per-wave [q=16][kv=64]
  int b = blockIdx.z, h = blockIdx.y, bx = blockIdx.x;
  int khd = h >> 2;
  int tid = threadIdx.x, w = tid >> 6, l = tid & 63;
  int lr = l & 15, lg = l >> 4;
  const unsigned short* K = kbuf + (size_t)(b * NKV + khd) * S_LEN * HD;
  const unsigned short* VT = vtbuf + (size_t)(b * NKV + khd) * HD * S_LEN;
  char* klp = (char*)k_lds;
  char* vlp = (char*)v_lds;
  char* plp = (char*)p_lds[w];
  int swz = (lr & 7) << 4;   // row&7 == lr&7 for all our row = 16*c + lr reads

  for (int strip = 0; strip < 2; ++strip) {
    int qs = strip ? (15 - bx) : bx;
    int q0 = qs * 64;
    const unsigned short* Q = qh + ((size_t)(b * NHQ + h) * S_LEN + q0 + w * 16) * HD;
    bf16x8 qf[4];
#pragma unroll
    for (int kk = 0; kk < 4; ++kk)
      qf[kk] = *(const bf16x8*)&Q[(size_t)lr * HD + kk * 32 + lg * 8];

    f32x4 o[8] = {};
    float m_[4], l_[4];
#pragma unroll
    for (int j = 0; j < 4; ++j) { m_[j] = -1e30f; l_[j] = 0.0f; }

    int nt = qs + 1;
    for (int t = 0; t < nt; ++t) {
      int t0 = t * 64;
      __syncthreads();
      // stage K (64x128, 256B rows) and VT (128x64, 128B rows), source pre-swizzled
#pragma unroll
      for (int it = 0; it < 4; ++it) {
        int db = (tid + it * 256) * 16;
        int kr = db >> 8, kc = db & 255;
        gload_lds16(K + (size_t)(t0 + kr) * HD + ((kc ^ ((kr & 7) << 4)) >> 1), klp + db);
        int vr = db >> 7, vc = db & 127;
        gload_lds16(VT + (size_t)vr * S_LEN + t0 + ((vc ^ ((vr & 7) << 4)) >> 1), vlp + db);
      }
      __syncthreads();

      // QK^T: per wave 16q x 64k
      f32x4 sc[4];
      __builtin_amdgcn_s_setprio(1);
#pragma unroll
      for (int ct = 0; ct < 4; ++ct) {
        f32x4 s = {};
        int row = ct * 16 + lr;
#pragma unroll
        for (int kk = 0; kk < 4; ++kk) {
          bf16x8 kf = *(const bf16x8*)(klp + row * 256 + ((kk * 64 + lg * 16) ^ swz));
          s = __builtin_amdgcn_mfma_f32_16x16x32_bf16(qf[kk], kf, s, 0, 0, 0);
        }
        sc[ct] = s;
      }
      __builtin_amdgcn_s_setprio(0);

      bool full = (t < qs);   // only the last tile is causally partial
      float alpha[4];
#pragma unroll
      for (int j = 0; j < 4; ++j) {
        if (!full) {
          int rg = q0 + w * 16 + lg * 4 + j;
#pragma unroll
          for (int ct = 0; ct < 4; ++ct)
            sc[ct][j] = (t0 + ct * 16 + lr <= rg) ? sc[ct][j] : -1e30f;
        }
        float mx = fmaxf(fmaxf(sc[0][j], sc[1][j]), fmaxf(sc[2][j], sc[3][j]));
#pragma unroll
        for (int msk = 1; msk < 16; msk <<= 1) mx = fmaxf(mx, __shfl_xor(mx, msk, 64));
        float mn = fmaxf(m_[j], mx);
        alpha[j] = __expf(m_[j] - mn);
        int q = lg * 4 + j;
        int psw = (q & 7) << 4;
        float ps = 0.0f;
#pragma unroll
        for (int ct = 0; ct < 4; ++ct) {
          float p = __expf(sc[ct][j] - mn);
          ps += p;
          *(unsigned short*)(plp + q * 128 + (((ct * 16 + lr) * 2) ^ psw)) = f2bf(p);
        }
#pragma unroll
        for (int msk = 1; msk < 16; msk <<= 1) ps += __shfl_xor(ps, msk, 64);
        l_[j] = l_[j] * alpha[j] + ps;
        m_[j] = mn;
      }
#pragma unroll
      for (int dc = 0; dc < 8; ++dc) {
        o[dc][0] *= alpha[0]; o[dc][1] *= alpha[1];
        o[dc][2] *= alpha[2]; o[dc][3] *= alpha[3];
      }
      // PV: p_lds is wave-private; ensure our ds_writes landed before frag reads
      asm volatile("s_waitcnt lgkmcnt(0)" ::: "memory");
      __builtin_amdgcn_s_setprio(1);
#pragma unroll
      for (int kt = 0; kt < 2; ++kt) {
        bf16x8 pa = *(const bf16x8*)(plp + lr * 128 + ((kt * 64 + lg * 16) ^ swz));
#pragma unroll
        for (int dc = 0; dc < 8; ++dc) {
          int vrow = dc * 16 + lr;
          bf16x8 vf = *(const bf16x8*)(vlp + vrow * 128 + ((kt * 64 + lg * 16) ^ swz));
          o[dc] = __builtin_amdgcn_mfma_f32_16x16x32_bf16(pa, vf, o[dc], 0, 0, 0);
        }
      }
      __builtin_amdgcn_s_setprio(0);
    }

#pragma unroll
    for (int j = 0; j < 4; ++j) {
      int rg = q0 + w * 16 + lg * 4 + j;
      size_t row = (size_t)(b * S_LEN + rg) * D_MODEL + h * HD;
      float inv = 1.0f / l_[j];
#pragma unroll
      for (int dc = 0; dc < 8; ++dc)
        attn_out[row + dc * 16 + lr] = f2bf(o[dc][j] * inv);
    }
  }
}

extern "C" void kernel_launch(void* const* d_in, const int* in_sizes, int n_in,
                              void* d_out, int out_size, void* d_ws, size_t ws_size,
                              hipStream_t stream) {
  const float* x        = (const float*)d_in[0];
  const int* positions  = (const int*)d_in[1];
  const float* wq       = (const float*)d_in[2];
  const float* wk       = (const float*)d_in[3];
  const float* wv       = (const float*)d_in[4];
  const float* wo       = (const float*)d_in[5];
  const float* qnw      = (const float*)d_in[6];
  const float* knw      = (const float*)d_in[7];
  float* out            = (float*)d_out;

  // workspace layout (144 MB total, with lifetime-based reuse)
  char* ws = (char*)d_ws;
  unsigned short* xb   = (unsigned short*)(ws);                    // 16.78 MB  [x bf16]  -> later attn_out
  unsigned short* wB   = (unsigned short*)(ws + 16777216);         // 50.33 MB  [qkv weights bf16 T] -> later q/k/vt
  unsigned short* woT  = (unsigned short*)(ws + 67108864);         // 33.55 MB  [wo bf16 T]
  float*          qkv  = (float*)(ws + 100663296);                 // 50.33 MB  [qkv f32]
  unsigned short* qh   = wB;                                        // 16.78 MB
  unsigned short* khb  = (unsigned short*)(ws + 33554432);          //  4.19 MB
  unsigned short* vtb  = (unsigned short*)(ws + 37748736);          //  4.19 MB
  unsigned short* attn = xb;                                        // 16.78 MB

  dim3 tb(256);
  // zero-init out (GEMM2 accumulates with atomics)
  hipMemsetAsync(out, 0, (size_t)out_size * 4, stream);

  k_f32_to_bf16<<<4096, tb, 0, stream>>>(x, xb, 1048576);
  k_transpose<<<dim3(128, 128), tb, 0, stream>>>(wq, wB, 4096, 4096);
  k_transpose<<<dim3(32, 128), tb, 0, stream>>>(wk, wB + (size_t)4096 * 4096, 4096, 1024);
  k_transpose<<<dim3(32, 128), tb, 0, stream>>>(wv, wB + (size_t)5120 * 4096, 4096, 1024);
  k_transpose<<<dim3(128, 128), tb, 0, stream>>>(wo, woT, 4096, 4096);

  // GEMM1: [2048][4096] x [6144][4096]^T -> qkv f32 [2048][6144]  (192 blocks)
  k_gemm256<<<dim3(192), dim3(512), 131072, stream>>>(xb, wB, qkv, 4096, 6144, 24, 1, 64, 0);

  k_norm_rope<<<16384, tb, 0, stream>>>(qkv, qnw, positions, qh, 32, 0, SM_SCALE);
  k_norm_rope<<<4096, tb, 0, stream>>>(qkv, knw, positions, khb, 8, 4096, 1.0f);
  k_v_transpose<<<dim3(4, 32, 16), tb, 0, stream>>>(qkv, vtb);

  k_attn<<<dim3(8, 32, 2), tb, 0, stream>>>(qh, khb, vtb, attn);

  // GEMM2: [2048][4096] x [4096][4096]^T -> out f32, K-split x2 + atomicAdd (256 blocks)
  k_gemm256<<<dim3(256), dim3(512), 131072, stream>>>(attn, woT, out, 4096, 4096, 16, 2, 32, 1);
}

// Round 6
// 324.151 us; speedup vs baseline: 1.1581x; 1.1581x over previous
//
#include <hip/hip_runtime.h>
#include <stdint.h>

// Problem constants
#define S_LEN   1024
#define D_MODEL 4096
#define NHQ     32
#define NKV     8
#define HD      128
#define NTOK    2048   // B*S
#define NQKV    6144   // 4096 q + 1024 k + 1024 v
#define SM_SCALE 0.08838834764831843f

typedef __attribute__((ext_vector_type(8))) __bf16 bf16x8;
typedef __attribute__((ext_vector_type(4))) float f32x4;

__device__ __forceinline__ unsigned short f2bf(float f) {
  union { float f; unsigned u; } x; x.f = f;
  unsigned r = x.u + 0x7fffu + ((x.u >> 16) & 1u);
  return (unsigned short)(r >> 16);
}
__device__ __forceinline__ float bf2f(unsigned short u) {
  union { unsigned u; float f; } x; x.u = (unsigned)u << 16; return x.f;
}

__device__ __forceinline__ void gload_lds16(const void* g, void* l) {
  __builtin_amdgcn_global_load_lds((__attribute__((address_space(1))) void*)g,
                                   (__attribute__((address_space(3))) void*)l,
                                   16, 0, 0);
}

// ---------------- f32 -> bf16 straight conversion (vectorized) ----------------
__global__ void k_f32_to_bf16(const float* __restrict__ in,
                              unsigned short* __restrict__ out, int n8) {
  int i = blockIdx.x * blockDim.x + threadIdx.x;
  if (i >= n8) return;
  const float4* p = (const float4*)(in + (size_t)i * 8);
  float4 v0 = p[0], v1 = p[1];
  uint4 o;
  o.x = f2bf(v0.x) | ((unsigned)f2bf(v0.y) << 16);
  o.y = f2bf(v0.z) | ((unsigned)f2bf(v0.w) << 16);
  o.z = f2bf(v1.x) | ((unsigned)f2bf(v1.y) << 16);
  o.w = f2bf(v1.z) | ((unsigned)f2bf(v1.w) << 16);
  *(uint4*)(out + (size_t)i * 8) = o;
}

// ---------------- f32 [R][C] -> bf16 [C][R] tiled transpose ----------------
__global__ void k_transpose(const float* __restrict__ in,
                            unsigned short* __restrict__ out, int R, int C) {
  __shared__ float t[32][33];
  int c = threadIdx.x & 31, r0 = threadIdx.x >> 5;   // 256 threads: 8 rows x 32 cols
  int cb = blockIdx.x * 32, rb = blockIdx.y * 32;
#pragma unroll
  for (int i = 0; i < 4; ++i) {
    int r = r0 + i * 8;
    t[r][c] = in[(size_t)(rb + r) * C + cb + c];
  }
  __syncthreads();
#pragma unroll
  for (int i = 0; i < 4; ++i) {
    int r = r0 + i * 8;
    out[(size_t)(cb + r) * R + rb + c] = f2bf(t[c][r]);
  }
}

// ================= 256xBN pipelined bf16 GEMM (round-4 sync template) =========
// C[M][ldc](OutT) = A[M][K](bf16) * Bt[N][K](bf16)^T
// NF = B-frags per wave: NF=4 -> BN=256 (per-wave 128x64), NF=2 -> BN=128
// (per-wave 128x32, full-chip grids). 512 thr = 8 waves (2M x 4N), BK=64,
// dbuf over K-tiles. Per K-tile 4 quadrant-phases; gates vmcnt(2+NF/2) at
// q1/q3 only (never 0). Race audit: identical to round-4 (verified passing);
// NF=2 gate arithmetic re-derived: gate leaves exactly the 2+NF/2 loads of
// the not-yet-read half outstanding.
// XCD 2D supergroup: per XCD a SGM x SGN block sub-grid (L2 working set
// ~0.5MB/K-tile instead of streaming all of B per XCD).
// LDS: per-buf A 32KB + B NF*8KB; 64-B rows, slot^=(row>>1)&3 (0 conflicts).

#define STGA(ksrc, half, bufi)                                                  \
  { int kcl = (ksrc) < NT ? (ksrc) : NT - 1;                                    \
    _Pragma("unroll")                                                           \
    for (int i_ = 0; i_ < 2; ++i_) {                                            \
      int lin = i_ * 512 + tid;                                                 \
      int r_ = lin >> 2, slot = lin & 3;                                        \
      int sw = slot ^ ((r_ >> 1) & 3);                                          \
      gload_lds16(Aptr + (size_t)(bm + r_) * Kstride + kcl * 64 + (half) * 32 + sw * 8, \
                  smem + (bufi) * BUFST + (half) * 16384 + lin * 16);           \
    } }

#define STGB(ksrc, half, bufi)                                                  \
  { int kcl = (ksrc) < NT ? (ksrc) : NT - 1;                                    \
    _Pragma("unroll")                                                           \
    for (int i_ = 0; i_ < NF / 2; ++i_) {                                       \
      int lin = i_ * 512 + tid;                                                 \
      int r_ = lin >> 2, slot = lin & 3;                                        \
      int sw = slot ^ ((r_ >> 1) & 3);                                          \
      gload_lds16(Bptr + (size_t)(bn + r_) * Kstride + kcl * 64 + (half) * 32 + sw * 8, \
                  smem + (bufi) * BUFST + 32768 + (half) * (NF * 4096) + lin * 16); \
    } }

#define RD_A(mh, kh, bufi)                                                      \
  _Pragma("unroll")                                                             \
  for (int mf = 0; mf < 4; ++mf) {                                              \
    int row = wr * 128 + (mh) * 64 + mf * 16 + lr;                              \
    af[mf] = *(const bf16x8*)(smem + (bufi) * BUFST + (kh) * 16384 + row * 64   \
                              + ((lg * 16) ^ (((row >> 1) & 3) << 4)));         \
  }

#define RD_B(kh, bufi)                                                          \
  _Pragma("unroll")                                                             \
  for (int nf = 0; nf < NF; ++nf) {                                             \
    int row = wc * NF * 16 + nf * 16 + lr;                                      \
    bf[nf] = *(const bf16x8*)(smem + (bufi) * BUFST + 32768 + (kh) * (NF * 4096) \
                              + row * 64 + ((lg * 16) ^ (((row >> 1) & 3) << 4))); \
  }

#define GATEW                                                                   \
  { if constexpr (NF == 4) asm volatile("s_waitcnt vmcnt(4)" ::: "memory");     \
    else                   asm volatile("s_waitcnt vmcnt(3)" ::: "memory"); }

#define PHASE_TAIL(mh, GATE)                                                    \
  if (GATE) GATEW                                                               \
  __builtin_amdgcn_s_barrier();                                                 \
  asm volatile("s_waitcnt lgkmcnt(0)" ::: "memory");                            \
  __builtin_amdgcn_sched_barrier(0);                                            \
  __builtin_amdgcn_s_setprio(1);                                                \
  _Pragma("unroll")                                                             \
  for (int mf = 0; mf < 4; ++mf)                                                \
    _Pragma("unroll")                                                           \
    for (int nf = 0; nf < NF; ++nf)                                             \
      acc[(mh) * 4 + mf][nf] = __builtin_amdgcn_mfma_f32_16x16x32_bf16(         \
          af[mf], bf[nf], acc[(mh) * 4 + mf][nf], 0, 0, 0);                     \
  __builtin_amdgcn_s_setprio(0);                                                \
  __builtin_amdgcn_s_barrier();

template <int NF, typename OutT>
__global__ __launch_bounds__(512, 1) void k_gemm256(
    const unsigned short* __restrict__ Aptr,
    const unsigned short* __restrict__ Bptr,
    OutT* __restrict__ C, int Kstride, int ldc, int NT, int SGN, int nxn) {
  extern __shared__ __align__(16) char smem[];
  constexpr int BUFST = 32768 + NF * 8192;
  int tid = threadIdx.x;
  int l = tid & 63;
  int w = tid >> 6;
  int lr = l & 15, lg = l >> 4;
  int wr = w >> 2, wc = w & 3;
  // XCD 2D supergroup: XCD x = blockIdx%8 owns a SGM x SGN sub-grid
  int per_xcd = gridDim.x >> 3;
  int x8 = blockIdx.x & 7, i = blockIdx.x >> 3;
  int SGM = per_xcd / SGN;
  int xr = x8 / nxn, xc = x8 - xr * nxn;
  int iy = i / SGN;
  int by = xr * SGM + iy, bx = xc * SGN + (i - iy * SGN);
  int bm = by * 256, bn = bx * NF * 64;

  f32x4 acc[8][NF] = {};
  bf16x8 af[4], bf[NF];

  // prologue: stage K-tile 0 (both halves); gate -> h0 complete; publish.
  STGA(0, 0, 0) STGB(0, 0, 0)
  STGA(0, 1, 0) STGB(0, 1, 0)
  GATEW
  __builtin_amdgcn_s_barrier();

  for (int kt = 0; kt < NT; ++kt) {
    int cur = kt & 1;
    RD_A(0, 0, cur) RD_B(0, cur)
    STGA(kt + 1, 0, cur ^ 1)
    PHASE_TAIL(0, 0)
    RD_A(1, 0, cur)
    STGB(kt + 1, 0, cur ^ 1)
    PHASE_TAIL(1, 1)
    RD_A(0, 1, cur) RD_B(1, cur)
    STGA(kt + 1, 1, cur ^ 1)
    PHASE_TAIL(0, 0)
    RD_A(1, 1, cur)
    STGB(kt + 1, 1, cur ^ 1)
    PHASE_TAIL(1, 1)
  }

  // epilogue: C/D layout col=lane&15, row=(lane>>4)*4+j [m89-verified]
#pragma unroll
  for (int mh = 0; mh < 2; ++mh)
#pragma unroll
    for (int mf = 0; mf < 4; ++mf)
#pragma unroll
      for (int nf = 0; nf < NF; ++nf)
#pragma unroll
        for (int j = 0; j < 4; ++j) {
          size_t idx = (size_t)(bm + wr * 128 + mh * 64 + mf * 16 + lg * 4 + j) * ldc +
                       bn + wc * NF * 16 + nf * 16 + lr;
          float v = acc[mh * 4 + mf][nf][j];
          if constexpr (sizeof(OutT) == 2) C[idx] = f2bf(v);
          else C[idx] = v;
        }
}

// ---------------- RMSNorm + RoPE, bf16 qkv -> bf16 head-major ----------------
// out layout: [B][nheads][S][HD]; oscale folds softmax scale into Q
__global__ void k_norm_rope(const unsigned short* __restrict__ qkv,
                            const float* __restrict__ w,
                            const int* __restrict__ positions,
                            unsigned short* __restrict__ out, int nheads, int colbase,
                            float oscale) {
  int wid = blockIdx.x * 4 + (threadIdx.x >> 6);
  int lane = threadIdx.x & 63;
  int token = wid / nheads, head = wid - token * nheads;
  const unsigned short* src = qkv + (size_t)token * NQKV + colbase + head * HD;
  float e0 = bf2f(src[lane]), e1 = bf2f(src[lane + 64]);
  float ss = e0 * e0 + e1 * e1;
#pragma unroll
  for (int m = 1; m < 64; m <<= 1) ss += __shfl_xor(ss, m, 64);
  float rs = rsqrtf(ss * (1.0f / 128.0f) + 1e-6f);
  float n0 = e0 * rs * w[lane], n1 = e1 * rs * w[lane + 64];
  int pos = positions[token];
  // inv_freq = theta^(-lane/64) ; log2(1e6) = 19.931568569324174
  float invf = exp2f((float)lane * (-19.931568569324174f / 64.0f));
  float ang = (float)pos * invf;
  float sv, cv;
  sincosf(ang, &sv, &cv);
  float o0 = (n0 * cv - n1 * sv) * oscale;
  float o1 = (n1 * cv + n0 * sv) * oscale;
  int b = token >> 10, s = token & 1023;
  size_t ob = ((size_t)(b * nheads + head) * S_LEN + s) * HD;
  out[ob + lane] = f2bf(o0);
  out[ob + 64 + lane] = f2bf(o1);
}

// ---------------- V transpose: bf16 qkv v-cols -> bf16 [b][kv][d][s] ----------
__global__ void k_v_transpose(const unsigned short* __restrict__ qkv,
                              unsigned short* __restrict__ vt) {
  __shared__ unsigned short t[32][33];
  int slice = blockIdx.z;              // b*8 + kh
  int b = slice >> 3, kh = slice & 7;
  const unsigned short* in = qkv + (size_t)(b * S_LEN) * NQKV + 5120 + kh * HD;
  unsigned short* out = vt + (size_t)slice * HD * S_LEN;
  int c = threadIdx.x & 31, r0 = threadIdx.x >> 5;
  int s0 = blockIdx.y * 32, d0 = blockIdx.x * 32;
#pragma unroll
  for (int i = 0; i < 4; ++i) {
    int r = r0 + i * 8;
    t[r][c] = in[(size_t)(s0 + r) * NQKV + d0 + c];
  }
  __syncthreads();
#pragma unroll
  for (int i = 0; i < 4; ++i) {
    int r = r0 + i * 8;
    out[(size_t)(d0 + r) * S_LEN + s0 + c] = t[c][r];
  }
}

// ---------------- causal GQA flash attention ----------------
// Q: [B][32][S][128] bf16 (pre-scaled by SM_SCALE) ; K: [B][8][S][128] bf16 ;
// VT: [B][8][128][S] bf16 ; out: attn [NTOK][4096] bf16
// KVBLK=64, XOR-swizzled LDS (byte ^= (row&7)<<4, both-sides), strip pairing
// (bx, 15-bx) for uniform per-block work.
__global__ __launch_bounds__(256) void k_attn(const unsigned short* __restrict__ qh,
                                              const unsigned short* __restrict__ kbuf,
                                              const unsigned short* __restrict__ vtbuf,
                                              unsigned short* __restrict__ attn_out) {
  __shared__ __align__(16) unsigned short k_lds[64 * 128];   // [kv=64][d=128]
  __shared__ __align__(16) unsigned short v_lds[128 * 64];   // [d=128][kv=64]
  __shared__ __align__(16) unsigned short p_lds[4][16 * 64]; // per-wave [q=16][kv=64]
  int b = blockIdx.z, h = blockIdx.y, bx = blockIdx.x;
  int khd = h >> 2;
  int tid = threadIdx.x, w = tid >> 6, l = tid & 63;
  int lr = l & 15, lg = l >> 4;
  const unsigned short* K = kbuf + (size_t)(b * NKV + khd) * S_LEN * HD;
  const unsigned short* VT = vtbuf + (size_t)(b * NKV + khd) * HD * S_LEN;
  char* klp = (char*)k_lds;
  char* vlp = (char*)v_lds;
  char* plp = (char*)p_lds[w];
  int swz = (lr & 7) << 4;   // row&7 == lr&7 for all our row = 16*c + lr reads

  for (int strip = 0; strip < 2; ++strip) {
    int qs = strip ? (15 - bx) : bx;
    int q0 = qs * 64;
    const unsigned short* Q = qh + ((size_t)(b * NHQ + h) * S_LEN + q0 + w * 16) * HD;
    bf16x8 qf[4];
#pragma unroll
    for (int kk = 0; kk < 4; ++kk)
      qf[kk] = *(const bf16x8*)&Q[(size_t)lr * HD + kk * 32 + lg * 8];

    f32x4 o[8] = {};
    float m_[4], l_[4];
#pragma unroll
    for (int j = 0; j < 4; ++j) { m_[j] = -1e30f; l_[j] = 0.0f; }

    int nt = qs + 1;
    for (int t = 0; t < nt; ++t) {
      int t0 = t * 64;
      __syncthreads();
      // stage K (64x128, 256B rows) and VT (128x64, 128B rows), source pre-swizzled
#pragma unroll
      for (int it = 0; it < 4; ++it) {
        int db = (tid + it * 256) * 16;
        int kr = db >> 8, kc = db & 255;
        gload_lds16(K + (size_t)(t0 + kr) * HD + ((kc ^ ((kr & 7) << 4)) >> 1), klp + db);
        int vr = db >> 7, vc = db & 127;
        gload_lds16(VT + (size_t)vr * S_LEN + t0 + ((vc ^ ((vr & 7) << 4)) >> 1), vlp + db);
      }
      __syncthreads();

      // QK^T: per wave 16q x 64k
      f32x4 sc[4];
      __builtin_amdgcn_s_setprio(1);
#pragma unroll
      for (int ct = 0; ct < 4; ++ct) {
        f32x4 s = {};
        int row = ct * 16 + lr;
#pragma unroll
        for (int kk = 0; kk < 4; ++kk) {
          bf16x8 kf = *(const bf16x8*)(klp + row * 256 + ((kk * 64 + lg * 16) ^ swz));
          s = __builtin_amdgcn_mfma_f32_16x16x32_bf16(qf[kk], kf, s, 0, 0, 0);
        }
        sc[ct] = s;
      }
      __builtin_amdgcn_s_setprio(0);

      bool full = (t < qs);   // only the last tile is causally partial
      float alpha[4];
#pragma unroll
      for (int j = 0; j < 4; ++j) {
        if (!full) {
          int rg = q0 + w * 16 + lg * 4 + j;
#pragma unroll
          for (int ct = 0; ct < 4; ++ct)
            sc[ct][j] = (t0 + ct * 16 + lr <= rg) ? sc[ct][j] : -1e30f;
        }
        float mx = fmaxf(fmaxf(sc[0][j], sc[1][j]), fmaxf(sc[2][j], sc[3][j]));
#pragma unroll
        for (int msk = 1; msk < 16; msk <<= 1) mx = fmaxf(mx, __shfl_xor(mx, msk, 64));
        float mn = fmaxf(m_[j], mx);
        alpha[j] = __expf(m_[j] - mn);
        int q = lg * 4 + j;
        int psw = (q & 7) << 4;
        float ps = 0.0f;
#pragma unroll
        for (int ct = 0; ct < 4; ++ct) {
          float p = __expf(sc[ct][j] - mn);
          ps += p;
          *(unsigned short*)(plp + q * 128 + (((ct * 16 + lr) * 2) ^ psw)) = f2bf(p);
        }
#pragma unroll
        for (int msk = 1; msk < 16; msk <<= 1) ps += __shfl_xor(ps, msk, 64);
        l_[j] = l_[j] * alpha[j] + ps;
        m_[j] = mn;
      }
#pragma unroll
      for (int dc = 0; dc < 8; ++dc) {
        o[dc][0] *= alpha[0]; o[dc][1] *= alpha[1];
        o[dc][2] *= alpha[2]; o[dc][3] *= alpha[3];
      }
      // PV: p_lds is wave-private; ensure our ds_writes landed before frag reads
      asm volatile("s_waitcnt lgkmcnt(0)" ::: "memory");
      __builtin_amdgcn_s_setprio(1);
#pragma unroll
      for (int kt = 0; kt < 2; ++kt) {
        bf16x8 pa = *(const bf16x8*)(plp + lr * 128 + ((kt * 64 + lg * 16) ^ swz));
#pragma unroll
        for (int dc = 0; dc < 8; ++dc) {
          int vrow = dc * 16 + lr;
          bf16x8 vf = *(const bf16x8*)(vlp + vrow * 128 + ((kt * 64 + lg * 16) ^ swz));
          o[dc] = __builtin_amdgcn_mfma_f32_16x16x32_bf16(pa, vf, o[dc], 0, 0, 0);
        }
      }
      __builtin_amdgcn_s_setprio(0);
    }

#pragma unroll
    for (int j = 0; j < 4; ++j) {
      int rg = q0 + w * 16 + lg * 4 + j;
      size_t row = (size_t)(b * S_LEN + rg) * D_MODEL + h * HD;
      float inv = 1.0f / l_[j];
#pragma unroll
      for (int dc = 0; dc < 8; ++dc)
        attn_out[row + dc * 16 + lr] = f2bf(o[dc][j] * inv);
    }
  }
}

extern "C" void kernel_launch(void* const* d_in, const int* in_sizes, int n_in,
                              void* d_out, int out_size, void* d_ws, size_t ws_size,
                              hipStream_t stream) {
  const float* x        = (const float*)d_in[0];
  const int* positions  = (const int*)d_in[1];
  const float* wq       = (const float*)d_in[2];
  const float* wk       = (const float*)d_in[3];
  const float* wv       = (const float*)d_in[4];
  const float* wo       = (const float*)d_in[5];
  const float* qnw      = (const float*)d_in[6];
  const float* knw      = (const float*)d_in[7];
  float* out            = (float*)d_out;

  // workspace layout (144 MB total, with lifetime-based reuse)
  char* ws = (char*)d_ws;
  unsigned short* xb   = (unsigned short*)(ws);                    // 16.78 MB  [x bf16]  -> later attn_out
  unsigned short* wB   = (unsigned short*)(ws + 16777216);         // 50.33 MB  [qkv weights bf16 T] -> later q/k/vt
  unsigned short* woT  = (unsigned short*)(ws + 67108864);         // 33.55 MB  [wo bf16 T]
  unsigned short* qkvb = (unsigned short*)(ws + 100663296);        // 25.17 MB  [qkv bf16]
  unsigned short* qh   = wB;                                        // 16.78 MB
  unsigned short* khb  = (unsigned short*)(ws + 33554432);          //  4.19 MB
  unsigned short* vtb  = (unsigned short*)(ws + 37748736);          //  4.19 MB
  unsigned short* attn = xb;                                        // 16.78 MB

  dim3 tb(256);
  k_f32_to_bf16<<<4096, tb, 0, stream>>>(x, xb, 1048576);
  k_transpose<<<dim3(128, 128), tb, 0, stream>>>(wq, wB, 4096, 4096);
  k_transpose<<<dim3(32, 128), tb, 0, stream>>>(wk, wB + (size_t)4096 * 4096, 4096, 1024);
  k_transpose<<<dim3(32, 128), tb, 0, stream>>>(wv, wB + (size_t)5120 * 4096, 4096, 1024);
  k_transpose<<<dim3(128, 128), tb, 0, stream>>>(wo, woT, 4096, 4096);

  // GEMM1: [2048][4096] x [6144][4096]^T -> qkv bf16 [2048][6144]
  // grid 192 = 8 XCD x (4bm x 6bn) supergroup
  k_gemm256<4, unsigned short><<<dim3(192), dim3(512), 131072, stream>>>(
      xb, wB, qkvb, 4096, 6144, 64, 6, 4);

  k_norm_rope<<<16384, tb, 0, stream>>>(qkvb, qnw, positions, qh, 32, 0, SM_SCALE);
  k_norm_rope<<<4096, tb, 0, stream>>>(qkvb, knw, positions, khb, 8, 4096, 1.0f);
  k_v_transpose<<<dim3(4, 32, 16), tb, 0, stream>>>(qkvb, vtb);

  k_attn<<<dim3(8, 32, 2), tb, 0, stream>>>(qh, khb, vtb, attn);

  // GEMM2: [2048][4096] x [4096][4096]^T -> out f32 [2048][4096]
  // BN=128: grid 256 = full chip, no K-split/atomics; 8 XCD x (4bm x 8bn)
  k_gemm256<2, float><<<dim3(256), dim3(512), 98304, stream>>>(
      attn, woT, out, 4096, 4096, 64, 8, 4);
}